// Round 8
// baseline (156.195 us; speedup 1.0000x reference)
//
#include <hip/hip_runtime.h>

// HolonomyAttention: out = softmax_causal((Q @ C_h) K^T / sqrt(D)) V
// B=2 H=16 T=2048 D=64, fp32 in/out.
// Round 17: packing fix. r16 counters proved all variants are tail-limited
// (occupancy 10.5% = 3.4 waves/CU; CU makespan = one block's 32 serial
// tiles). This round: uniform work units = (bh, 128-row block p, j-chunk
// of <=8 tiles) -> 1280 blocks depth<=8, 4 waves x 32 rows (VGPR~68 ->
// 16 waves/CU resident), LDS dbuf staging as r16. Multi-chunk units write
// unnormalized fp32 partials (O,l); combine kernel (cross-kernel ordering
// = XCD-coherence-safe) sums <=4 partials, normalizes, stores. p<=3 units
// (single chunk) store directly.
// prep kernels unchanged (plane-split frag layout).

typedef __attribute__((ext_vector_type(8))) short short8;           // 8 bf16
typedef __attribute__((ext_vector_type(8))) unsigned short ushort8;
typedef __attribute__((ext_vector_type(4))) float f32x4;
typedef __attribute__((ext_vector_type(2))) _Float16 half2v;
typedef __attribute__((ext_vector_type(4))) _Float16 half4;
typedef __attribute__((ext_vector_type(8))) _Float16 half8;

constexpr int Tc = 2048;
constexpr int Dc = 64;
constexpr size_t REGION = (size_t)32 * Tc * Dc;   // 4,194,304 elems = 8 MiB u16

__device__ inline unsigned short f2bf(float f) {   // fp32 -> bf16 RNE
    union { float f; unsigned u; } x; x.f = f;
    return (unsigned short)((x.u + 0x7fffu + ((x.u >> 16) & 1u)) >> 16);
}

__device__ inline half2v pkrtz(float a, float b) {
    return __builtin_bit_cast(half2v, __builtin_amdgcn_cvt_pkrtz(a, b));
}

#define MFMA_BF16_K32(a, b, c) __builtin_amdgcn_mfma_f32_16x16x32_bf16((a), (b), (c), 0, 0, 0)
#define MFMA_F16_K16(a, b, c)  __builtin_amdgcn_mfma_f32_16x16x16f16((a), (b), (c), 0, 0, 0)

// async global->LDS copy: per-lane global addr, wave-uniform LDS base,
// HW deposits at base + lane*16.
typedef __attribute__((address_space(3))) unsigned int        lds_u32;
typedef const __attribute__((address_space(1))) unsigned int  glob_u32;
__device__ __attribute__((always_inline)) inline void gl_lds16(const void* g, void* l) {
    __builtin_amdgcn_global_load_lds((glob_u32*)g, (lds_u32*)l, 16, 0, 0);
}

// ---------------------------------------------------------------------------
// Kernel 0: C^T B-operand fragments per head (tiny, one-time).
// ---------------------------------------------------------------------------
__global__ __launch_bounds__(256, 1)
void holo_cfrag(const float* __restrict__ Cp, unsigned short* __restrict__ cfrag_g)
{
    const int t = threadIdx.x, lane = t & 63, eb = t >> 6;
    const int l15 = lane & 15, quad = lane >> 4;
    const int h = blockIdx.x;
    const float* Cg = Cp + (size_t)h * Dc * Dc;
    #pragma unroll
    for (int half = 0; half < 2; ++half) {
        short8 b;
        #pragma unroll
        for (int jj = 0; jj < 8; ++jj) {
            const int d = half * 32 + quad * 8 + jj;
            b[jj] = (short)f2bf(Cg[d * Dc + eb * 16 + l15]);
        }
        *(short8*)(&cfrag_g[(((size_t)h * 4 + eb) * 2 + half) * 512 + lane * 8]) = b;
    }
}

// ---------------------------------------------------------------------------
// Kernel 1: prepass, one block per (bh, 64-row tile st). LDS-staged.
// K/V fragment tiles PLANE-SPLIT within each 8KB tile (unchanged).
// ---------------------------------------------------------------------------
__global__ __launch_bounds__(256, 4)
void holo_prep8(const float* __restrict__ Qp, const float* __restrict__ Kp,
                const float* __restrict__ Vp,
                const unsigned short* __restrict__ cfrag_g,
                unsigned short* __restrict__ qfrag_g,
                unsigned short* __restrict__ kfrag_g,
                _Float16* __restrict__ vfrag_g)
{
    __shared__ unsigned short kt[64 * 72];   // K tile bf16 natural [s][d]
    __shared__ unsigned short qt[64 * 72];   // Q tile bf16 natural [r][d]
    __shared__ _Float16      vt[64 * 72];    // V tile f16 natural [s][d]
    __shared__ unsigned short pf[64 * 72];   // Qrot C->B-frag round trip

    const int t = threadIdx.x, lane = t & 63, w = t >> 6;
    const int l15 = lane & 15, quad = lane >> 4, wb = w * 16;
    const int n = blockIdx.x, bh = n >> 5, st = n & 31, h = bh & 15;
    const int s0 = st * 64;

    const float* Qg = Qp + ((size_t)bh * Tc + s0) * Dc;
    const float* Kg = Kp + ((size_t)bh * Tc + s0) * Dc;
    const float* Vg = Vp + ((size_t)bh * Tc + s0) * Dc;

    // ---- stage all three tiles (coalesced float4 reads, cvt, LDS write) ----
    #pragma unroll
    for (int kk = 0; kk < 4; ++kk) {
        const int flat = kk * 1024 + t * 4;
        const int r = flat >> 6, d0 = flat & 63;
        float4 kv = *(const float4*)(&Kg[flat]);
        ushort4 kp; kp.x = f2bf(kv.x); kp.y = f2bf(kv.y); kp.z = f2bf(kv.z); kp.w = f2bf(kv.w);
        *(ushort4*)(&kt[r * 72 + d0]) = kp;
        float4 qv = *(const float4*)(&Qg[flat]);
        ushort4 qp; qp.x = f2bf(qv.x); qp.y = f2bf(qv.y); qp.z = f2bf(qv.z); qp.w = f2bf(qv.w);
        *(ushort4*)(&qt[r * 72 + d0]) = qp;
        float4 vv = *(const float4*)(&Vg[flat]);
        half4 vp;
        vp[0] = (_Float16)vv.x; vp[1] = (_Float16)vv.y;
        vp[2] = (_Float16)vv.z; vp[3] = (_Float16)vv.w;
        *(half4*)(&vt[r * 72 + d0]) = vp;
    }
    __syncthreads();

    // ---- K fragments (wave w handles tn = w): plane-split writes ----
    {
        const int row = wb + l15;
        ushort8 p0 = *(const ushort8*)(&kt[row * 72 + quad * 8]);
        ushort8 p1 = *(const ushort8*)(&kt[row * 72 + 32 + quad * 8]);
        unsigned short* ktile = kfrag_g + (size_t)(bh * 32 + st) * 4096;
        *(ushort8*)(&ktile[(w * 64 + lane) * 8])        = p0;
        *(ushort8*)(&ktile[2048 + (w * 64 + lane) * 8]) = p1;
    }

    // ---- V fragments: plane-split writes ----
    {
        half8 v0, v1;
        #pragma unroll
        for (int dn = 0; dn < 2; ++dn)
            #pragma unroll
            for (int i = 0; i < 4; ++i)
                v0[dn * 4 + i] = vt[(wb + quad * 4 + i) * 72 + dn * 16 + l15];
        #pragma unroll
        for (int dn = 0; dn < 2; ++dn)
            #pragma unroll
            for (int i = 0; i < 4; ++i)
                v1[dn * 4 + i] = vt[(wb + quad * 4 + i) * 72 + (dn + 2) * 16 + l15];
        _Float16* vtile = vfrag_g + (size_t)(bh * 32 + st) * 4096;
        *(half8*)(&vtile[(w * 64 + lane) * 8])        = v0;
        *(half8*)(&vtile[2048 + (w * 64 + lane) * 8]) = v1;
    }

    // ---- Qrot strip (rows s0+wb..+15): A from qt LDS, B from cfrag ----
    {
        short8 a0 = *(const short8*)(&qt[(wb + l15) * 72 + quad * 8]);
        short8 a1 = *(const short8*)(&qt[(wb + l15) * 72 + 32 + quad * 8]);
        #pragma unroll
        for (int eb = 0; eb < 4; ++eb) {
            short8 b0 = *(const short8*)(&cfrag_g[(((size_t)h * 4 + eb) * 2 + 0) * 512 + lane * 8]);
            short8 b1 = *(const short8*)(&cfrag_g[(((size_t)h * 4 + eb) * 2 + 1) * 512 + lane * 8]);
            f32x4 c = {0.f, 0.f, 0.f, 0.f};
            c = MFMA_BF16_K32(a0, b0, c);
            c = MFMA_BF16_K32(a1, b1, c);
            #pragma unroll
            for (int i = 0; i < 4; ++i)   // fold 0.125 * log2(e)
                pf[(wb + quad * 4 + i) * 72 + eb * 16 + l15] = f2bf(c[i] * 0.18033688f);
        }
        __threadfence_block();   // wave-local rows: order writes before reads
        short8 fa0 = *(const short8*)(&pf[(wb + l15) * 72 + quad * 8]);
        short8 fa1 = *(const short8*)(&pf[(wb + l15) * 72 + 32 + quad * 8]);
        const size_t strip = (size_t)bh * 128 + st * 4 + w;
        *(short8*)(&qfrag_g[strip * 1024 + lane * 8]) = fa0;
        *(short8*)(&qfrag_g[strip * 1024 + 512 + lane * 8]) = fa1;
    }
}

// ---------------------------------------------------------------------------
// Kernel 2: attention, uniform-depth chunks. 1 block = (bh, p, c):
// 128 q-rows (p), j-tiles [8c, min(8c+8, 2p+2)). 4 waves x 32 rows.
// LDS dbuf staging; JIT ds_read_b128. nch==1 -> direct store; else write
// unnormalized fp32 partial (O, l) for the combine kernel.
// ---------------------------------------------------------------------------
__global__ __launch_bounds__(256, 4)
void holo_attn17(const unsigned short* __restrict__ qfrag_g,
                 const unsigned short* __restrict__ kfrag_g,
                 const _Float16* __restrict__ vfrag_g,
                 float* __restrict__ opart_g,
                 float* __restrict__ lpart_g,
                 float* __restrict__ Op)
{
    __shared__ unsigned short bufK[2][4096];   // 2 x 8KB, plane-split layout
    __shared__ _Float16      bufV[2][4096];    // 2 x 8KB

    const int t = threadIdx.x, lane = t & 63, wid = t >> 6;   // wid 0..3
    const int l15 = lane & 15, quad = lane >> 4;

    // decode block -> (bh, p, c). 1280 = 8 xcd * 4 bh * 40 chunks.
    const int id = blockIdx.x;
    const int xcd = id & 7, s = id >> 3;       // s: 0..159
    const int bh = xcd * 4 + (s & 3);
    int rem = s >> 2;                          // 0..39
    int p = 0;
    while (true) { const int nc = (2 * p + 9) >> 3; if (rem < nc) break; rem -= nc; ++p; }
    const int c = rem;
    const int nch = (2 * p + 9) >> 3;          // chunks for this p (1..4)
    const int j0 = c * 8;
    const int jlim = 2 * p + 2;
    const int j1 = (j0 + 8 < jlim) ? j0 + 8 : jlim;
    const int jdiag = 2 * p + (wid >> 1);      // this wave's diagonal tile

    const char* kbase = (const char*)(kfrag_g + (size_t)bh * 32 * 4096);
    const char* vbase = (const char*)(vfrag_g + (size_t)bh * 32 * 4096);

    // ---- stage tile j0 into ring slot 0 (4 loads per wave) ----
    {
        const char* ks = kbase + (size_t)j0 * 8192;
        const char* vs = vbase + (size_t)j0 * 8192;
        gl_lds16(ks + wid * 1024 + lane * 16,        &bufK[0][wid * 512]);
        gl_lds16(ks + 4096 + wid * 1024 + lane * 16, &bufK[0][2048 + wid * 512]);
        gl_lds16(vs + wid * 1024 + lane * 16,        &bufV[0][wid * 512]);
        gl_lds16(vs + 4096 + wid * 1024 + lane * 16, &bufV[0][2048 + wid * 512]);
    }

    // Qrot B-fragments for this wave's two strips (scale*log2e folded in)
    short8 qa0[2], qa1[2];
    #pragma unroll
    for (int s2 = 0; s2 < 2; ++s2) {
        const size_t strip = (size_t)bh * 128 + p * 8 + wid * 2 + s2;
        qa0[s2] = *(const short8*)(&qfrag_g[strip * 1024 + lane * 8]);
        qa1[s2] = *(const short8*)(&qfrag_g[strip * 1024 + 512 + lane * 8]);
    }

    f32x4 o[2][4];              // o[s2][dn][i]: O[q=l15][d=dn*16+quad*4+i]
    #pragma unroll
    for (int s2 = 0; s2 < 2; ++s2)
        #pragma unroll
        for (int dn = 0; dn < 4; ++dn) o[s2][dn] = f32x4{0.f, 0.f, 0.f, 0.f};
    float l2[2] = {0.f, 0.f};

    const int rowgA = p * 128 + wid * 32 + l15;   // strip 0 global q row
    const int rowgB = rowgA + 16;                 // strip 1

    asm volatile("s_waitcnt vmcnt(0)" ::: "memory");
    __builtin_amdgcn_sched_barrier(0);
    __syncthreads();

    int cur = 0;
    for (int j = j0; j < j1; ++j) {
        // ---- issue next tile's DMA into the other ring slot ----
        if (j + 1 < j1) {
            const char* ks = kbase + (size_t)(j + 1) * 8192;
            const char* vs = vbase + (size_t)(j + 1) * 8192;
            const int nb = cur ^ 1;
            gl_lds16(ks + wid * 1024 + lane * 16,        &bufK[nb][wid * 512]);
            gl_lds16(ks + 4096 + wid * 1024 + lane * 16, &bufK[nb][2048 + wid * 512]);
            gl_lds16(vs + wid * 1024 + lane * 16,        &bufV[nb][wid * 512]);
            gl_lds16(vs + 4096 + wid * 1024 + lane * 16, &bufV[nb][2048 + wid * 512]);
        }

        // waves 0,1 have no valid rows on tile 2p+1: skip compute
        // (wave-uniform) but still hit the barrier below.
        if (j <= jdiag) {
            const unsigned short* Kl = &bufK[cur][0];
            const _Float16*       Vl = &bufV[cur][0];

            // ---- S^T = K * Qrot^T, both strips share K regs ----
            f32x4 stA[4], stB[4];
            __builtin_amdgcn_s_setprio(1);
            #pragma unroll
            for (int tn = 0; tn < 4; ++tn) {
                short8 k0 = *(const short8*)(&Kl[(tn * 64 + lane) * 8]);
                short8 k1 = *(const short8*)(&Kl[2048 + (tn * 64 + lane) * 8]);
                f32x4 cA = {0.f, 0.f, 0.f, 0.f};
                cA = MFMA_BF16_K32(k0, qa0[0], cA);
                cA = MFMA_BF16_K32(k1, qa1[0], cA);
                stA[tn] = cA;
                f32x4 cB = {0.f, 0.f, 0.f, 0.f};
                cB = MFMA_BF16_K32(k0, qa0[1], cB);
                cB = MFMA_BF16_K32(k1, qa1[1], cB);
                stB[tn] = cB;
            }
            __builtin_amdgcn_s_setprio(0);

            // ---- mask + fixed-shift softmax; packed f16 cvt ----
            half4 paA[4], paB[4];
            #pragma unroll
            for (int tn = 0; tn < 4; ++tn) {
                float pA[4];
                #pragma unroll
                for (int i = 0; i < 4; ++i) {
                    float sv = stA[tn][i];
                    if (j == jdiag) {
                        const int colg = j * 64 + tn * 16 + quad * 4 + i;
                        if (colg > rowgA) sv = -1e30f;
                    }
                    pA[i] = __builtin_amdgcn_exp2f(sv);
                    l2[0] += pA[i];
                }
                half2v lo = pkrtz(pA[0], pA[1]), hi = pkrtz(pA[2], pA[3]);
                paA[tn] = __builtin_shufflevector(lo, hi, 0, 1, 2, 3);
            }
            #pragma unroll
            for (int tn = 0; tn < 4; ++tn) {
                float pB[4];
                #pragma unroll
                for (int i = 0; i < 4; ++i) {
                    float sv = stB[tn][i];
                    if (j == jdiag) {
                        const int colg = j * 64 + tn * 16 + quad * 4 + i;
                        if (colg > rowgB) sv = -1e30f;
                    }
                    pB[i] = __builtin_amdgcn_exp2f(sv);
                    l2[1] += pB[i];
                }
                half2v lo = pkrtz(pB[0], pB[1]), hi = pkrtz(pB[2], pB[3]);
                paB[tn] = __builtin_shufflevector(lo, hi, 0, 1, 2, 3);
            }

            // ---- O^T += V^T * P, both strips share V regs ----
            __builtin_amdgcn_s_setprio(1);
            #pragma unroll
            for (int tn = 0; tn < 4; ++tn) {
                half8 vl = *(const half8*)(&Vl[(tn * 64 + lane) * 8]);
                half8 vh = *(const half8*)(&Vl[2048 + (tn * 64 + lane) * 8]);
                half4 vf0 = __builtin_shufflevector(vl, vl, 0, 1, 2, 3);
                half4 vf1 = __builtin_shufflevector(vl, vl, 4, 5, 6, 7);
                half4 vf2 = __builtin_shufflevector(vh, vh, 0, 1, 2, 3);
                half4 vf3 = __builtin_shufflevector(vh, vh, 4, 5, 6, 7);
                o[0][0] = MFMA_F16_K16(vf0, paA[tn], o[0][0]);
                o[0][1] = MFMA_F16_K16(vf1, paA[tn], o[0][1]);
                o[0][2] = MFMA_F16_K16(vf2, paA[tn], o[0][2]);
                o[0][3] = MFMA_F16_K16(vf3, paA[tn], o[0][3]);
                o[1][0] = MFMA_F16_K16(vf0, paB[tn], o[1][0]);
                o[1][1] = MFMA_F16_K16(vf1, paB[tn], o[1][1]);
                o[1][2] = MFMA_F16_K16(vf2, paB[tn], o[1][2]);
                o[1][3] = MFMA_F16_K16(vf3, paB[tn], o[1][3]);
            }
            __builtin_amdgcn_s_setprio(0);
        }

        // ---- flip: next DMA landed + all waves done reading cur ----
        asm volatile("s_waitcnt vmcnt(0)" ::: "memory");
        __builtin_amdgcn_sched_barrier(0);
        __syncthreads();
        cur ^= 1;
    }

    // ---- per-strip row sums ----
    #pragma unroll
    for (int s2 = 0; s2 < 2; ++s2) {
        l2[s2] += __shfl_xor(l2[s2], 16);
        l2[s2] += __shfl_xor(l2[s2], 32);
    }

    if (nch == 1) {
        // single-chunk unit: normalize + direct store
        #pragma unroll
        for (int s2 = 0; s2 < 2; ++s2) {
            const float inv = 1.0f / l2[s2];
            const int rowg = rowgA + s2 * 16;
            float* dst = Op + ((size_t)bh * Tc + rowg) * Dc;
            #pragma unroll
            for (int dn = 0; dn < 4; ++dn) {
                float4 r;
                r.x = o[s2][dn][0] * inv; r.y = o[s2][dn][1] * inv;
                r.z = o[s2][dn][2] * inv; r.w = o[s2][dn][3] * inv;
                *(float4*)(&dst[dn * 16 + quad * 4]) = r;
            }
        }
    } else {
        // multi-chunk: write unnormalized fp32 partial (O, l)
        const size_t slot = (size_t)(bh * 16 + p) * 4 + c;
        #pragma unroll
        for (int s2 = 0; s2 < 2; ++s2) {
            const int prow = wid * 32 + s2 * 16 + l15;   // 0..127
            float* od = opart_g + slot * 8192 + (size_t)prow * 64;
            #pragma unroll
            for (int dn = 0; dn < 4; ++dn) {
                float4 r;
                r.x = o[s2][dn][0]; r.y = o[s2][dn][1];
                r.z = o[s2][dn][2]; r.w = o[s2][dn][3];
                *(float4*)(&od[dn * 16 + quad * 4]) = r;
            }
            if (quad == 0) lpart_g[slot * 128 + prow] = l2[s2];
        }
    }
}

// ---------------------------------------------------------------------------
// Kernel 3: combine partials for multi-chunk units (p >= 4).
// 384 blocks = 32 bh x 12 p. out = (sum_c O_c) / (sum_c l_c).
// Cross-kernel dispatch ordering guarantees partial visibility (XCD-safe).
// ---------------------------------------------------------------------------
__global__ __launch_bounds__(256, 4)
void holo_comb(const float* __restrict__ opart_g,
               const float* __restrict__ lpart_g,
               float* __restrict__ Op)
{
    const int u2 = blockIdx.x;                 // 0..383
    const int bh = u2 / 12, p = 4 + (u2 % 12);
    const int nch = (2 * p + 9) >> 3;          // 2..4
    const size_t ubase = (size_t)(bh * 16 + p) * 4;

    const int t = threadIdx.x;
    const int r = t >> 1, c0 = (t & 1) * 32;   // row 0..127, col half

    float acc[32];
    #pragma unroll
    for (int k = 0; k < 32; ++k) acc[k] = 0.f;
    float lsum = 0.f;

    for (int c = 0; c < nch; ++c) {
        const size_t slot = ubase + c;
        lsum += lpart_g[slot * 128 + r];
        const float* src = opart_g + slot * 8192 + (size_t)r * 64 + c0;
        #pragma unroll
        for (int k4 = 0; k4 < 8; ++k4) {
            float4 v = *(const float4*)(&src[k4 * 4]);
            acc[k4 * 4 + 0] += v.x; acc[k4 * 4 + 1] += v.y;
            acc[k4 * 4 + 2] += v.z; acc[k4 * 4 + 3] += v.w;
        }
    }

    const float inv = 1.0f / lsum;
    float* dst = Op + ((size_t)bh * Tc + p * 128 + r) * Dc + c0;
    #pragma unroll
    for (int k4 = 0; k4 < 8; ++k4) {
        float4 v;
        v.x = acc[k4 * 4 + 0] * inv; v.y = acc[k4 * 4 + 1] * inv;
        v.z = acc[k4 * 4 + 2] * inv; v.w = acc[k4 * 4 + 3] * inv;
        *(float4*)(&dst[k4 * 4]) = v;
    }
}

extern "C" void kernel_launch(void* const* d_in, const int* in_sizes, int n_in,
                              void* d_out, int out_size, void* d_ws, size_t ws_size,
                              hipStream_t stream) {
    const float* Q = (const float*)d_in[0];
    const float* K = (const float*)d_in[1];
    const float* V = (const float*)d_in[2];
    // d_in[3] = causal mask (analytic — unused)
    const float* C = (const float*)d_in[4];
    float* O = (float*)d_out;

    unsigned short* qfrag_w = (unsigned short*)d_ws;              // 8 MiB
    unsigned short* kfrag_w = qfrag_w + REGION;                   // 8 MiB
    _Float16*       vfrag_w = (_Float16*)(kfrag_w + REGION);      // 8 MiB
    unsigned short* cfrag_w = (unsigned short*)(vfrag_w + REGION);// 128 KiB
    float* opart_w = (float*)((char*)d_ws + ((size_t)25 << 20));  // 64 MiB (2048 slots x 32KB)
    float* lpart_w = (float*)((char*)d_ws + ((size_t)90 << 20));  // 1 MiB

    holo_cfrag<<<dim3(16), dim3(256), 0, stream>>>(C, cfrag_w);
    holo_prep8<<<dim3(1024), dim3(256), 0, stream>>>(Q, K, V, cfrag_w, qfrag_w, kfrag_w, vfrag_w);
    holo_attn17<<<dim3(1280), dim3(256), 0, stream>>>(qfrag_w, kfrag_w, vfrag_w, opart_w, lpart_w, O);
    holo_comb<<<dim3(384), dim3(256), 0, stream>>>(opart_w, lpart_w, O);
}

// Round 9
// 138.056 us; speedup vs baseline: 1.1314x; 1.1314x over previous
//
#include <hip/hip_runtime.h>

// HolonomyAttention: out = softmax_causal((Q @ C_h) K^T / sqrt(D)) V
// B=2 H=16 T=2048 D=64, fp32 in/out.
// Round 18: revert to r12 (best measured: reg-prefetch, parity split, no
// in-loop barriers, bounds(256,2)) -- r14/r15/r16/r17 proved LDS staging,
// coarse blocks, and chunking+partials are all neutral-to-worse; binding
// cost is the per-tile VALU softmax chain. One change: l = P*ones via an
// extra f16 MFMA per (tn,strip) -> deletes 64 VALU adds/tile/wave + the
// epilogue shuffle reduction (MFMA sums all k=16 across quads).
// prep kernels = r12 verbatim (interleaved frag layout).

typedef __attribute__((ext_vector_type(8))) short short8;           // 8 bf16
typedef __attribute__((ext_vector_type(8))) unsigned short ushort8;
typedef __attribute__((ext_vector_type(4))) float f32x4;
typedef __attribute__((ext_vector_type(2))) _Float16 half2v;
typedef __attribute__((ext_vector_type(4))) _Float16 half4;
typedef __attribute__((ext_vector_type(8))) _Float16 half8;

constexpr int Tc = 2048;
constexpr int Dc = 64;
constexpr size_t REGION = (size_t)32 * Tc * Dc;   // 4,194,304 elems = 8 MiB u16

__device__ inline unsigned short f2bf(float f) {   // fp32 -> bf16 RNE
    union { float f; unsigned u; } x; x.f = f;
    return (unsigned short)((x.u + 0x7fffu + ((x.u >> 16) & 1u)) >> 16);
}

__device__ inline half2v pkrtz(float a, float b) {
    return __builtin_bit_cast(half2v, __builtin_amdgcn_cvt_pkrtz(a, b));
}

#define MFMA_BF16_K32(a, b, c) __builtin_amdgcn_mfma_f32_16x16x32_bf16((a), (b), (c), 0, 0, 0)
#define MFMA_F16_K16(a, b, c)  __builtin_amdgcn_mfma_f32_16x16x16f16((a), (b), (c), 0, 0, 0)

// ---------------------------------------------------------------------------
// Kernel 0: C^T B-operand fragments per head (tiny, one-time).
// ---------------------------------------------------------------------------
__global__ __launch_bounds__(256, 1)
void holo_cfrag(const float* __restrict__ Cp, unsigned short* __restrict__ cfrag_g)
{
    const int t = threadIdx.x, lane = t & 63, eb = t >> 6;
    const int l15 = lane & 15, quad = lane >> 4;
    const int h = blockIdx.x;
    const float* Cg = Cp + (size_t)h * Dc * Dc;
    #pragma unroll
    for (int half = 0; half < 2; ++half) {
        short8 b;
        #pragma unroll
        for (int jj = 0; jj < 8; ++jj) {
            const int d = half * 32 + quad * 8 + jj;
            b[jj] = (short)f2bf(Cg[d * Dc + eb * 16 + l15]);
        }
        *(short8*)(&cfrag_g[(((size_t)h * 4 + eb) * 2 + half) * 512 + lane * 8]) = b;
    }
}

// ---------------------------------------------------------------------------
// Kernel 1: prepass, one block per (bh, 64-row tile st). LDS-staged.
// (r12 verbatim, interleaved frag layout)
// ---------------------------------------------------------------------------
__global__ __launch_bounds__(256, 4)
void holo_prep8(const float* __restrict__ Qp, const float* __restrict__ Kp,
                const float* __restrict__ Vp,
                const unsigned short* __restrict__ cfrag_g,
                unsigned short* __restrict__ qfrag_g,
                unsigned short* __restrict__ kfrag_g,
                _Float16* __restrict__ vfrag_g)
{
    __shared__ unsigned short kt[64 * 72];   // K tile bf16 natural [s][d]
    __shared__ unsigned short qt[64 * 72];   // Q tile bf16 natural [r][d]
    __shared__ _Float16      vt[64 * 72];    // V tile f16 natural [s][d]
    __shared__ unsigned short pf[64 * 72];   // Qrot C->B-frag round trip

    const int t = threadIdx.x, lane = t & 63, w = t >> 6;
    const int l15 = lane & 15, quad = lane >> 4, wb = w * 16;
    const int n = blockIdx.x, bh = n >> 5, st = n & 31, h = bh & 15;
    const int s0 = st * 64;

    const float* Qg = Qp + ((size_t)bh * Tc + s0) * Dc;
    const float* Kg = Kp + ((size_t)bh * Tc + s0) * Dc;
    const float* Vg = Vp + ((size_t)bh * Tc + s0) * Dc;

    // ---- stage all three tiles (coalesced float4 reads, cvt, LDS write) ----
    #pragma unroll
    for (int kk = 0; kk < 4; ++kk) {
        const int flat = kk * 1024 + t * 4;
        const int r = flat >> 6, d0 = flat & 63;
        float4 kv = *(const float4*)(&Kg[flat]);
        ushort4 kp; kp.x = f2bf(kv.x); kp.y = f2bf(kv.y); kp.z = f2bf(kv.z); kp.w = f2bf(kv.w);
        *(ushort4*)(&kt[r * 72 + d0]) = kp;
        float4 qv = *(const float4*)(&Qg[flat]);
        ushort4 qp; qp.x = f2bf(qv.x); qp.y = f2bf(qv.y); qp.z = f2bf(qv.z); qp.w = f2bf(qv.w);
        *(ushort4*)(&qt[r * 72 + d0]) = qp;
        float4 vv = *(const float4*)(&Vg[flat]);
        half4 vp;
        vp[0] = (_Float16)vv.x; vp[1] = (_Float16)vv.y;
        vp[2] = (_Float16)vv.z; vp[3] = (_Float16)vv.w;
        *(half4*)(&vt[r * 72 + d0]) = vp;
    }
    __syncthreads();

    // ---- K fragments (wave w handles tn = w): b128 LDS reads, coalesced writes
    {
        const int row = wb + l15;
        ushort8 p0 = *(const ushort8*)(&kt[row * 72 + quad * 8]);
        ushort8 p1 = *(const ushort8*)(&kt[row * 72 + 32 + quad * 8]);
        unsigned short* kdst = kfrag_g + (((size_t)(bh * 32 + st) * 4 + w) * 64 + lane) * 16;
        *(ushort8*)(kdst) = p0;
        *(ushort8*)(kdst + 8) = p1;
    }

    // ---- V fragments: scalar LDS reads (<=4-way banked), coalesced writes ----
    {
        half8 v0, v1;
        #pragma unroll
        for (int dn = 0; dn < 2; ++dn)
            #pragma unroll
            for (int i = 0; i < 4; ++i)
                v0[dn * 4 + i] = vt[(wb + quad * 4 + i) * 72 + dn * 16 + l15];
        #pragma unroll
        for (int dn = 0; dn < 2; ++dn)
            #pragma unroll
            for (int i = 0; i < 4; ++i)
                v1[dn * 4 + i] = vt[(wb + quad * 4 + i) * 72 + (dn + 2) * 16 + l15];
        _Float16* vdst = vfrag_g + (((size_t)(bh * 32 + st) * 4 + w) * 64 + lane) * 16;
        *(half8*)(vdst) = v0;
        *(half8*)(vdst + 8) = v1;
    }

    // ---- Qrot strip (rows s0+wb..+15): A from qt LDS, B from cfrag ----
    {
        short8 a0 = *(const short8*)(&qt[(wb + l15) * 72 + quad * 8]);
        short8 a1 = *(const short8*)(&qt[(wb + l15) * 72 + 32 + quad * 8]);
        #pragma unroll
        for (int eb = 0; eb < 4; ++eb) {
            short8 b0 = *(const short8*)(&cfrag_g[(((size_t)h * 4 + eb) * 2 + 0) * 512 + lane * 8]);
            short8 b1 = *(const short8*)(&cfrag_g[(((size_t)h * 4 + eb) * 2 + 1) * 512 + lane * 8]);
            f32x4 c = {0.f, 0.f, 0.f, 0.f};
            c = MFMA_BF16_K32(a0, b0, c);
            c = MFMA_BF16_K32(a1, b1, c);
            #pragma unroll
            for (int i = 0; i < 4; ++i)   // fold 0.125 * log2(e)
                pf[(wb + quad * 4 + i) * 72 + eb * 16 + l15] = f2bf(c[i] * 0.18033688f);
        }
        __threadfence_block();   // wave-local rows: order writes before reads
        short8 fa0 = *(const short8*)(&pf[(wb + l15) * 72 + quad * 8]);
        short8 fa1 = *(const short8*)(&pf[(wb + l15) * 72 + 32 + quad * 8]);
        const size_t strip = (size_t)bh * 128 + st * 4 + w;
        *(short8*)(&qfrag_g[strip * 1024 + lane * 8]) = fa0;
        *(short8*)(&qfrag_g[strip * 1024 + 512 + lane * 8]) = fa1;
    }
}

// ---------------------------------------------------------------------------
// Kernel 2: attention. r12 structure: 1 block = 1 (bh,qi) tile, 4 waves =
// (hv, parity); interleaved strip MFMA; reg prefetch; no in-loop barriers;
// bounds(256,2). New in r18: l computed via ones-A MFMA (full k=16 row sum
// on the matrix pipe) -- no VALU l-adds, no epilogue shuffles.
// ---------------------------------------------------------------------------
__global__ __launch_bounds__(256, 2)
void holo_attn18(const unsigned short* __restrict__ qfrag_g,
                 const unsigned short* __restrict__ kfrag_g,
                 const _Float16* __restrict__ vfrag_g,
                 float* __restrict__ Op)
{
    __shared__ float lds_o[2][2][16][68];   // [hv][s2][row][d] (+4 pad)
    __shared__ float lds_l[2][2][16];

    const int t = threadIdx.x, lane = t & 63, wid = t >> 6;
    const int l15 = lane & 15, quad = lane >> 4;
    const int hv  = wid & 1;      // row half: strips 2*hv, 2*hv+1
    const int par = wid >> 1;     // j parity

    // LPT + XCD-affine mapping: qi descends with dispatch order.
    const int id = blockIdx.x;
    const int xcd = id & 7, sseq = id >> 3;          // 128 blocks per XCD
    const int qi = 31 - (sseq >> 2);
    const int bh = xcd * 4 + (sseq & 3);
    const int q0 = qi * 64;

    // Qrot B-fragments for both strips (scale*log2e folded in)
    short8 qa0[2], qa1[2];
    #pragma unroll
    for (int s2 = 0; s2 < 2; ++s2) {
        const size_t strip = (size_t)bh * 128 + qi * 4 + (2 * hv + s2);
        qa0[s2] = *(const short8*)(&qfrag_g[strip * 1024 + lane * 8]);
        qa1[s2] = *(const short8*)(&qfrag_g[strip * 1024 + 512 + lane * 8]);
    }

    const unsigned short* kbase = kfrag_g + (size_t)bh * 32 * 4 * 1024;
    const _Float16*       vbase = vfrag_g + (size_t)bh * 32 * 4 * 1024;

    f32x4 o[2][4];                // o[s2][dn][i]: O[q=l15][d=dn*16+quad*4+i]
    f32x4 ol[2];                  // l accumulators via ones-MFMA (all 4 equal)
    #pragma unroll
    for (int s2 = 0; s2 < 2; ++s2) {
        #pragma unroll
        for (int dn = 0; dn < 4; ++dn) o[s2][dn] = f32x4{0.f, 0.f, 0.f, 0.f};
        ol[s2] = f32x4{0.f, 0.f, 0.f, 0.f};
    }
    const half4 vones = {(_Float16)1.f, (_Float16)1.f, (_Float16)1.f, (_Float16)1.f};

    const int rowgA = q0 + (2 * hv) * 16 + l15;   // strip 2hv global q row
    const int rowgB = rowgA + 16;                 // strip 2hv+1

    // preload K and V fragments for first tile j = par
    short8 kf0[4], kf1[4];
    half8 vlo[4], vhi[4];
    #pragma unroll
    for (int tn = 0; tn < 4; ++tn) {
        const unsigned short* kfb = kbase + (size_t)par * 4096 + ((size_t)tn * 64 + lane) * 16;
        kf0[tn] = *(const short8*)(kfb);
        kf1[tn] = *(const short8*)(kfb + 8);
        const _Float16* vfb = vbase + (size_t)par * 4096 + ((size_t)tn * 64 + lane) * 16;
        vlo[tn] = *(const half8*)(vfb);
        vhi[tn] = *(const half8*)(vfb + 8);
    }

    for (int j = par; j <= qi; j += 2) {
        const bool more = (j + 2 <= qi);
        const int jn = j + 2;

        // ---- S^T = K * Qrot^T for both strips (K regs resident) ----
        f32x4 stA[4], stB[4];
        __builtin_amdgcn_s_setprio(1);
        #pragma unroll
        for (int tn = 0; tn < 4; ++tn) {
            f32x4 cA = {0.f, 0.f, 0.f, 0.f};
            cA = MFMA_BF16_K32(kf0[tn], qa0[0], cA);
            cA = MFMA_BF16_K32(kf1[tn], qa1[0], cA);
            stA[tn] = cA;
            f32x4 cB = {0.f, 0.f, 0.f, 0.f};
            cB = MFMA_BF16_K32(kf0[tn], qa0[1], cB);
            cB = MFMA_BF16_K32(kf1[tn], qa1[1], cB);
            stB[tn] = cB;
        }
        __builtin_amdgcn_s_setprio(0);

        // ---- prefetch next tile's K (in place; K regs just consumed) ----
        if (more) {
            #pragma unroll
            for (int tn = 0; tn < 4; ++tn) {
                const unsigned short* kfb = kbase + (size_t)jn * 4096 + ((size_t)tn * 64 + lane) * 16;
                kf0[tn] = *(const short8*)(kfb);
                kf1[tn] = *(const short8*)(kfb + 8);
            }
        }

        // ---- mask + fixed-shift softmax; packed f16 cvt into B-regs ----
        half4 paA[4], paB[4];
        #pragma unroll
        for (int tn = 0; tn < 4; ++tn) {
            float pA[4], pB[4];
            #pragma unroll
            for (int i = 0; i < 4; ++i) {
                float svA = stA[tn][i], svB = stB[tn][i];
                if (j == qi) {
                    const int colg = j * 64 + tn * 16 + quad * 4 + i;
                    if (colg > rowgA) svA = -1e30f;
                    if (colg > rowgB) svB = -1e30f;
                }
                pA[i] = __builtin_amdgcn_exp2f(svA);
                pB[i] = __builtin_amdgcn_exp2f(svB);
            }
            half2v loA = pkrtz(pA[0], pA[1]), hiA = pkrtz(pA[2], pA[3]);
            paA[tn] = __builtin_shufflevector(loA, hiA, 0, 1, 2, 3);
            half2v loB = pkrtz(pB[0], pB[1]), hiB = pkrtz(pB[2], pB[3]);
            paB[tn] = __builtin_shufflevector(loB, hiB, 0, 1, 2, 3);
        }

        // ---- O^T += V^T * P for both strips (V regs resident); l via ones ----
        __builtin_amdgcn_s_setprio(1);
        #pragma unroll
        for (int tn = 0; tn < 4; ++tn) {
            half4 vf0 = __builtin_shufflevector(vlo[tn], vlo[tn], 0, 1, 2, 3);
            half4 vf1 = __builtin_shufflevector(vlo[tn], vlo[tn], 4, 5, 6, 7);
            half4 vf2 = __builtin_shufflevector(vhi[tn], vhi[tn], 0, 1, 2, 3);
            half4 vf3 = __builtin_shufflevector(vhi[tn], vhi[tn], 4, 5, 6, 7);
            o[0][0] = MFMA_F16_K16(vf0, paA[tn], o[0][0]);
            o[0][1] = MFMA_F16_K16(vf1, paA[tn], o[0][1]);
            o[0][2] = MFMA_F16_K16(vf2, paA[tn], o[0][2]);
            o[0][3] = MFMA_F16_K16(vf3, paA[tn], o[0][3]);
            o[1][0] = MFMA_F16_K16(vf0, paB[tn], o[1][0]);
            o[1][1] = MFMA_F16_K16(vf1, paB[tn], o[1][1]);
            o[1][2] = MFMA_F16_K16(vf2, paB[tn], o[1][2]);
            o[1][3] = MFMA_F16_K16(vf3, paB[tn], o[1][3]);
            ol[0]   = MFMA_F16_K16(vones, paA[tn], ol[0]);
            ol[1]   = MFMA_F16_K16(vones, paB[tn], ol[1]);
        }
        __builtin_amdgcn_s_setprio(0);

        // ---- prefetch next tile's V (in place; V regs just consumed) ----
        if (more) {
            #pragma unroll
            for (int tn = 0; tn < 4; ++tn) {
                const _Float16* vfb = vbase + (size_t)jn * 4096 + ((size_t)tn * 64 + lane) * 16;
                vlo[tn] = *(const half8*)(vfb);
                vhi[tn] = *(const half8*)(vfb + 8);
            }
        }
    }

    // l per strip = ol[s2][0] (MFMA summed the full k=16 across all quads;
    // every lane holds its q-row's partial sum for this parity).

    // ---- combine parity partials: par==1 publishes, par==0 sums + stores ----
    if (par == 1) {
        #pragma unroll
        for (int s2 = 0; s2 < 2; ++s2) {
            #pragma unroll
            for (int dn = 0; dn < 4; ++dn) {
                float4 r;
                r.x = o[s2][dn][0]; r.y = o[s2][dn][1];
                r.z = o[s2][dn][2]; r.w = o[s2][dn][3];
                *(float4*)(&lds_o[hv][s2][l15][dn * 16 + quad * 4]) = r;
            }
            if (quad == 0) lds_l[hv][s2][l15] = ol[s2][0];
        }
    }
    __syncthreads();
    if (par == 0) {
        #pragma unroll
        for (int s2 = 0; s2 < 2; ++s2) {
            const float inv = 1.0f / (ol[s2][0] + lds_l[hv][s2][l15]);
            const int rowg = q0 + (2 * hv + s2) * 16 + l15;
            float* dst = Op + ((size_t)bh * Tc + rowg) * Dc;
            const float* po = &lds_o[hv][s2][l15][0];
            #pragma unroll
            for (int dn = 0; dn < 4; ++dn) {
                float4 r;
                r.x = (o[s2][dn][0] + po[dn * 16 + quad * 4 + 0]) * inv;
                r.y = (o[s2][dn][1] + po[dn * 16 + quad * 4 + 1]) * inv;
                r.z = (o[s2][dn][2] + po[dn * 16 + quad * 4 + 2]) * inv;
                r.w = (o[s2][dn][3] + po[dn * 16 + quad * 4 + 3]) * inv;
                *(float4*)(&dst[dn * 16 + quad * 4]) = r;
            }
        }
    }
}

extern "C" void kernel_launch(void* const* d_in, const int* in_sizes, int n_in,
                              void* d_out, int out_size, void* d_ws, size_t ws_size,
                              hipStream_t stream) {
    const float* Q = (const float*)d_in[0];
    const float* K = (const float*)d_in[1];
    const float* V = (const float*)d_in[2];
    // d_in[3] = causal mask (analytic — unused)
    const float* C = (const float*)d_in[4];
    float* O = (float*)d_out;

    unsigned short* qfrag_w = (unsigned short*)d_ws;              // 8 MiB
    unsigned short* kfrag_w = qfrag_w + REGION;                   // 8 MiB
    _Float16*       vfrag_w = (_Float16*)(kfrag_w + REGION);      // 8 MiB
    unsigned short* cfrag_w = (unsigned short*)(vfrag_w + REGION);// 128 KiB

    holo_cfrag<<<dim3(16), dim3(256), 0, stream>>>(C, cfrag_w);
    holo_prep8<<<dim3(1024), dim3(256), 0, stream>>>(Q, K, V, cfrag_w, qfrag_w, kfrag_w, vfrag_w);
    holo_attn18<<<dim3(1024), dim3(256), 0, stream>>>(qfrag_w, kfrag_w, vfrag_w, O);
}

// Round 10
// 137.512 us; speedup vs baseline: 1.1359x; 1.0040x over previous
//
#include <hip/hip_runtime.h>

// HolonomyAttention: out = softmax_causal((Q @ C_h) K^T / sqrt(D)) V
// B=2 H=16 T=2048 D=64, fp32 in/out.
// Round 19 = Round 14 body with __launch_bounds__(256,4) on attn.
// Rationale: per-wave issue cost is additive across pipes (~430 cyc/tile);
// all ~34us variants ran 2 waves/SIMD. r14's JIT-ds_read body is VGPR~68
// (measured on r15's fatter sibling) -> legally 4 waves/SIMD. LDS 4x32KB
// = 128KB <= 160. Single-variable change: double TLP, same loop body.
// prep kernels unchanged (plane-split frag layout).

typedef __attribute__((ext_vector_type(8))) short short8;           // 8 bf16
typedef __attribute__((ext_vector_type(8))) unsigned short ushort8;
typedef __attribute__((ext_vector_type(4))) float f32x4;
typedef __attribute__((ext_vector_type(2))) _Float16 half2v;
typedef __attribute__((ext_vector_type(4))) _Float16 half4;
typedef __attribute__((ext_vector_type(8))) _Float16 half8;

constexpr int Tc = 2048;
constexpr int Dc = 64;
constexpr size_t REGION = (size_t)32 * Tc * Dc;   // 4,194,304 elems = 8 MiB u16

__device__ inline unsigned short f2bf(float f) {   // fp32 -> bf16 RNE
    union { float f; unsigned u; } x; x.f = f;
    return (unsigned short)((x.u + 0x7fffu + ((x.u >> 16) & 1u)) >> 16);
}

__device__ inline half2v pkrtz(float a, float b) {
    return __builtin_bit_cast(half2v, __builtin_amdgcn_cvt_pkrtz(a, b));
}

#define MFMA_BF16_K32(a, b, c) __builtin_amdgcn_mfma_f32_16x16x32_bf16((a), (b), (c), 0, 0, 0)
#define MFMA_F16_K16(a, b, c)  __builtin_amdgcn_mfma_f32_16x16x16f16((a), (b), (c), 0, 0, 0)

// async global->LDS copy: per-lane global addr, wave-uniform LDS base,
// HW deposits at base + lane*16.
typedef __attribute__((address_space(3))) unsigned int        lds_u32;
typedef const __attribute__((address_space(1))) unsigned int  glob_u32;
__device__ __attribute__((always_inline)) inline void gl_lds16(const void* g, void* l) {
    __builtin_amdgcn_global_load_lds((glob_u32*)g, (lds_u32*)l, 16, 0, 0);
}

// ---------------------------------------------------------------------------
// Kernel 0: C^T B-operand fragments per head (tiny, one-time).
// ---------------------------------------------------------------------------
__global__ __launch_bounds__(256, 1)
void holo_cfrag(const float* __restrict__ Cp, unsigned short* __restrict__ cfrag_g)
{
    const int t = threadIdx.x, lane = t & 63, eb = t >> 6;
    const int l15 = lane & 15, quad = lane >> 4;
    const int h = blockIdx.x;
    const float* Cg = Cp + (size_t)h * Dc * Dc;
    #pragma unroll
    for (int half = 0; half < 2; ++half) {
        short8 b;
        #pragma unroll
        for (int jj = 0; jj < 8; ++jj) {
            const int d = half * 32 + quad * 8 + jj;
            b[jj] = (short)f2bf(Cg[d * Dc + eb * 16 + l15]);
        }
        *(short8*)(&cfrag_g[(((size_t)h * 4 + eb) * 2 + half) * 512 + lane * 8]) = b;
    }
}

// ---------------------------------------------------------------------------
// Kernel 1: prepass, one block per (bh, 64-row tile st). LDS-staged.
// K/V fragment tiles PLANE-SPLIT within each 8KB tile:
//   ktile[0..2047]    = kf0 chunks, (tn*64+lane)*8 u16   (16B per lane)
//   ktile[2048..4095] = kf1 chunks
//   vtile likewise (v0 plane | v1 plane, f16)
// ---------------------------------------------------------------------------
__global__ __launch_bounds__(256, 4)
void holo_prep8(const float* __restrict__ Qp, const float* __restrict__ Kp,
                const float* __restrict__ Vp,
                const unsigned short* __restrict__ cfrag_g,
                unsigned short* __restrict__ qfrag_g,
                unsigned short* __restrict__ kfrag_g,
                _Float16* __restrict__ vfrag_g)
{
    __shared__ unsigned short kt[64 * 72];   // K tile bf16 natural [s][d]
    __shared__ unsigned short qt[64 * 72];   // Q tile bf16 natural [r][d]
    __shared__ _Float16      vt[64 * 72];    // V tile f16 natural [s][d]
    __shared__ unsigned short pf[64 * 72];   // Qrot C->B-frag round trip

    const int t = threadIdx.x, lane = t & 63, w = t >> 6;
    const int l15 = lane & 15, quad = lane >> 4, wb = w * 16;
    const int n = blockIdx.x, bh = n >> 5, st = n & 31, h = bh & 15;
    const int s0 = st * 64;

    const float* Qg = Qp + ((size_t)bh * Tc + s0) * Dc;
    const float* Kg = Kp + ((size_t)bh * Tc + s0) * Dc;
    const float* Vg = Vp + ((size_t)bh * Tc + s0) * Dc;

    // ---- stage all three tiles (coalesced float4 reads, cvt, LDS write) ----
    #pragma unroll
    for (int kk = 0; kk < 4; ++kk) {
        const int flat = kk * 1024 + t * 4;
        const int r = flat >> 6, d0 = flat & 63;
        float4 kv = *(const float4*)(&Kg[flat]);
        ushort4 kp; kp.x = f2bf(kv.x); kp.y = f2bf(kv.y); kp.z = f2bf(kv.z); kp.w = f2bf(kv.w);
        *(ushort4*)(&kt[r * 72 + d0]) = kp;
        float4 qv = *(const float4*)(&Qg[flat]);
        ushort4 qp; qp.x = f2bf(qv.x); qp.y = f2bf(qv.y); qp.z = f2bf(qv.z); qp.w = f2bf(qv.w);
        *(ushort4*)(&qt[r * 72 + d0]) = qp;
        float4 vv = *(const float4*)(&Vg[flat]);
        half4 vp;
        vp[0] = (_Float16)vv.x; vp[1] = (_Float16)vv.y;
        vp[2] = (_Float16)vv.z; vp[3] = (_Float16)vv.w;
        *(half4*)(&vt[r * 72 + d0]) = vp;
    }
    __syncthreads();

    // ---- K fragments (wave w handles tn = w): plane-split writes ----
    {
        const int row = wb + l15;
        ushort8 p0 = *(const ushort8*)(&kt[row * 72 + quad * 8]);
        ushort8 p1 = *(const ushort8*)(&kt[row * 72 + 32 + quad * 8]);
        unsigned short* ktile = kfrag_g + (size_t)(bh * 32 + st) * 4096;
        *(ushort8*)(&ktile[(w * 64 + lane) * 8])        = p0;
        *(ushort8*)(&ktile[2048 + (w * 64 + lane) * 8]) = p1;
    }

    // ---- V fragments: plane-split writes ----
    {
        half8 v0, v1;
        #pragma unroll
        for (int dn = 0; dn < 2; ++dn)
            #pragma unroll
            for (int i = 0; i < 4; ++i)
                v0[dn * 4 + i] = vt[(wb + quad * 4 + i) * 72 + dn * 16 + l15];
        #pragma unroll
        for (int dn = 0; dn < 2; ++dn)
            #pragma unroll
            for (int i = 0; i < 4; ++i)
                v1[dn * 4 + i] = vt[(wb + quad * 4 + i) * 72 + (dn + 2) * 16 + l15];
        _Float16* vtile = vfrag_g + (size_t)(bh * 32 + st) * 4096;
        *(half8*)(&vtile[(w * 64 + lane) * 8])        = v0;
        *(half8*)(&vtile[2048 + (w * 64 + lane) * 8]) = v1;
    }

    // ---- Qrot strip (rows s0+wb..+15): A from qt LDS, B from cfrag ----
    {
        short8 a0 = *(const short8*)(&qt[(wb + l15) * 72 + quad * 8]);
        short8 a1 = *(const short8*)(&qt[(wb + l15) * 72 + 32 + quad * 8]);
        #pragma unroll
        for (int eb = 0; eb < 4; ++eb) {
            short8 b0 = *(const short8*)(&cfrag_g[(((size_t)h * 4 + eb) * 2 + 0) * 512 + lane * 8]);
            short8 b1 = *(const short8*)(&cfrag_g[(((size_t)h * 4 + eb) * 2 + 1) * 512 + lane * 8]);
            f32x4 c = {0.f, 0.f, 0.f, 0.f};
            c = MFMA_BF16_K32(a0, b0, c);
            c = MFMA_BF16_K32(a1, b1, c);
            #pragma unroll
            for (int i = 0; i < 4; ++i)   // fold 0.125 * log2(e)
                pf[(wb + quad * 4 + i) * 72 + eb * 16 + l15] = f2bf(c[i] * 0.18033688f);
        }
        __threadfence_block();   // wave-local rows: order writes before reads
        short8 fa0 = *(const short8*)(&pf[(wb + l15) * 72 + quad * 8]);
        short8 fa1 = *(const short8*)(&pf[(wb + l15) * 72 + 32 + quad * 8]);
        const size_t strip = (size_t)bh * 128 + st * 4 + w;
        *(short8*)(&qfrag_g[strip * 1024 + lane * 8]) = fa0;
        *(short8*)(&qfrag_g[strip * 1024 + 512 + lane * 8]) = fa1;
    }
}

// ---------------------------------------------------------------------------
// Kernel 2: attention. 1 block = 1 (bh,qi) tile, 4 waves = 4 row strips.
// LDS double-buffered K+V staging via global_load_lds; JIT ds_read_b128
// operands; one barrier per tile; direct stores. r19: bounds(256,4) ->
// 4 blocks/CU, 16 waves/CU, 4 waves/SIMD (VGPR ~68 fits under 128).
// ---------------------------------------------------------------------------
__global__ __launch_bounds__(256, 4)
void holo_attn19(const unsigned short* __restrict__ qfrag_g,
                 const unsigned short* __restrict__ kfrag_g,
                 const _Float16* __restrict__ vfrag_g,
                 float* __restrict__ Op)
{
    __shared__ unsigned short bufK[2][4096];   // 2 x 8KB, plane-split layout
    __shared__ _Float16      bufV[2][4096];    // 2 x 8KB

    const int t = threadIdx.x, lane = t & 63, wid = t >> 6;
    const int l15 = lane & 15, quad = lane >> 4;

    // LPT + XCD-affine mapping: qi descends with dispatch order.
    const int id = blockIdx.x;
    const int xcd = id & 7, sseq = id >> 3;          // 128 blocks per XCD
    const int qi = 31 - (sseq >> 2);
    const int bh = xcd * 4 + (sseq & 3);
    const int q0 = qi * 64;

    const char* kbase = (const char*)(kfrag_g + (size_t)bh * 32 * 4096);
    const char* vbase = (const char*)(vfrag_g + (size_t)bh * 32 * 4096);

    // ---- stage tile 0 into ring slot 0 (async, issued first) ----
    {
        gl_lds16(kbase + wid * 1024 + lane * 16,        &bufK[0][wid * 512]);
        gl_lds16(kbase + 4096 + wid * 1024 + lane * 16, &bufK[0][2048 + wid * 512]);
        gl_lds16(vbase + wid * 1024 + lane * 16,        &bufV[0][wid * 512]);
        gl_lds16(vbase + 4096 + wid * 1024 + lane * 16, &bufV[0][2048 + wid * 512]);
    }

    // Qrot B-fragments for this wave's strip (scale*log2e folded in)
    short8 qa0, qa1;
    {
        const size_t strip = (size_t)bh * 128 + qi * 4 + wid;
        qa0 = *(const short8*)(&qfrag_g[strip * 1024 + lane * 8]);
        qa1 = *(const short8*)(&qfrag_g[strip * 1024 + 512 + lane * 8]);
    }

    f32x4 o[4];                 // o[dn][i]: O[q=l15][d=dn*16+quad*4+i]
    #pragma unroll
    for (int dn = 0; dn < 4; ++dn) o[dn] = f32x4{0.f, 0.f, 0.f, 0.f};
    float l_lane = 0.f;
    const int rowg = q0 + wid * 16 + l15;   // this lane's global q row

    asm volatile("s_waitcnt vmcnt(0)" ::: "memory");
    __builtin_amdgcn_sched_barrier(0);
    __syncthreads();

    int cur = 0;
    for (int j = 0; j <= qi; ++j) {
        // ---- issue next tile's DMA into the other ring slot ----
        if (j < qi) {
            const char* ks = kbase + (size_t)(j + 1) * 8192;
            const char* vs = vbase + (size_t)(j + 1) * 8192;
            const int nb = cur ^ 1;
            gl_lds16(ks + wid * 1024 + lane * 16,        &bufK[nb][wid * 512]);
            gl_lds16(ks + 4096 + wid * 1024 + lane * 16, &bufK[nb][2048 + wid * 512]);
            gl_lds16(vs + wid * 1024 + lane * 16,        &bufV[nb][wid * 512]);
            gl_lds16(vs + 4096 + wid * 1024 + lane * 16, &bufV[nb][2048 + wid * 512]);
        }

        const unsigned short* Kl = &bufK[cur][0];
        const _Float16*       Vl = &bufV[cur][0];

        // ---- S^T = K * Qrot^T : JIT ds_read_b128 per tn ----
        f32x4 st[4];
        __builtin_amdgcn_s_setprio(1);
        #pragma unroll
        for (int tn = 0; tn < 4; ++tn) {
            short8 k0 = *(const short8*)(&Kl[(tn * 64 + lane) * 8]);
            short8 k1 = *(const short8*)(&Kl[2048 + (tn * 64 + lane) * 8]);
            f32x4 c = {0.f, 0.f, 0.f, 0.f};
            c = MFMA_BF16_K32(k0, qa0, c);
            c = MFMA_BF16_K32(k1, qa1, c);
            st[tn] = c;
        }
        __builtin_amdgcn_s_setprio(0);

        // ---- mask + fixed-shift softmax; packed f16 cvt into B-regs ----
        half4 pa[4];
        #pragma unroll
        for (int tn = 0; tn < 4; ++tn) {
            float p[4];
            #pragma unroll
            for (int i = 0; i < 4; ++i) {
                float sv = st[tn][i];
                if (j == qi) {
                    const int colg = j * 64 + tn * 16 + quad * 4 + i;
                    if (colg > rowg) sv = -1e30f;
                }
                p[i] = __builtin_amdgcn_exp2f(sv);
                l_lane += p[i];
            }
            half2v lo = pkrtz(p[0], p[1]), hi = pkrtz(p[2], p[3]);
            pa[tn] = __builtin_shufflevector(lo, hi, 0, 1, 2, 3);
        }

        // ---- O^T += V^T * P : JIT ds_read_b128 per tn ----
        __builtin_amdgcn_s_setprio(1);
        #pragma unroll
        for (int tn = 0; tn < 4; ++tn) {
            half8 vl = *(const half8*)(&Vl[(tn * 64 + lane) * 8]);
            half8 vh = *(const half8*)(&Vl[2048 + (tn * 64 + lane) * 8]);
            half4 vf0 = __builtin_shufflevector(vl, vl, 0, 1, 2, 3);
            half4 vf1 = __builtin_shufflevector(vl, vl, 4, 5, 6, 7);
            half4 vf2 = __builtin_shufflevector(vh, vh, 0, 1, 2, 3);
            half4 vf3 = __builtin_shufflevector(vh, vh, 4, 5, 6, 7);
            o[0] = MFMA_F16_K16(vf0, pa[tn], o[0]);
            o[1] = MFMA_F16_K16(vf1, pa[tn], o[1]);
            o[2] = MFMA_F16_K16(vf2, pa[tn], o[2]);
            o[3] = MFMA_F16_K16(vf3, pa[tn], o[3]);
        }
        __builtin_amdgcn_s_setprio(0);

        // ---- flip: next DMA landed + all waves done reading cur ----
        asm volatile("s_waitcnt vmcnt(0)" ::: "memory");
        __builtin_amdgcn_sched_barrier(0);
        __syncthreads();
        cur ^= 1;
    }

    // ---- finish l: sum the 4 quad-partials per q=l15 ----
    l_lane += __shfl_xor(l_lane, 16);
    l_lane += __shfl_xor(l_lane, 32);
    const float inv = 1.0f / l_lane;

    // ---- epilogue: coalesced float4 stores (O^T C-layout) ----
    float* dst = Op + ((size_t)bh * Tc + rowg) * Dc;
    #pragma unroll
    for (int dn = 0; dn < 4; ++dn) {
        float4 r;
        r.x = o[dn][0] * inv; r.y = o[dn][1] * inv;
        r.z = o[dn][2] * inv; r.w = o[dn][3] * inv;
        *(float4*)(&dst[dn * 16 + quad * 4]) = r;
    }
}

extern "C" void kernel_launch(void* const* d_in, const int* in_sizes, int n_in,
                              void* d_out, int out_size, void* d_ws, size_t ws_size,
                              hipStream_t stream) {
    const float* Q = (const float*)d_in[0];
    const float* K = (const float*)d_in[1];
    const float* V = (const float*)d_in[2];
    // d_in[3] = causal mask (analytic — unused)
    const float* C = (const float*)d_in[4];
    float* O = (float*)d_out;

    unsigned short* qfrag_w = (unsigned short*)d_ws;              // 8 MiB
    unsigned short* kfrag_w = qfrag_w + REGION;                   // 8 MiB
    _Float16*       vfrag_w = (_Float16*)(kfrag_w + REGION);      // 8 MiB
    unsigned short* cfrag_w = (unsigned short*)(vfrag_w + REGION);// 128 KiB

    holo_cfrag<<<dim3(16), dim3(256), 0, stream>>>(C, cfrag_w);
    holo_prep8<<<dim3(1024), dim3(256), 0, stream>>>(Q, K, V, cfrag_w, qfrag_w, kfrag_w, vfrag_w);
    holo_attn19<<<dim3(1024), dim3(256), 0, stream>>>(qfrag_w, kfrag_w, vfrag_w, O);
}